// Round 4
// baseline (978.363 us; speedup 1.0000x reference)
//
#include <hip/hip_runtime.h>
#include <cstdint>
#include <cstddef>

typedef unsigned short ushort_t;
typedef unsigned int   uint_t;

#define B_   8
#define T_   16
#define N_   196
#define C_   768
#define H_   12
#define C3_  2304
#define M_   25088   // B_*T_*N_

typedef __attribute__((ext_vector_type(8))) short short8;
typedef __attribute__((ext_vector_type(4))) float floatx4;

__device__ __forceinline__ float bf2f(ushort_t u) {
  return __uint_as_float(((uint_t)u) << 16);
}
__device__ __forceinline__ ushort_t f2bf(float f) {
  uint_t u = __float_as_uint(f);
  u += 0x7FFFu + ((u >> 16) & 1u);   // round-to-nearest-even
  return (ushort_t)(u >> 16);
}
__device__ __forceinline__ uint_t pack2(float a, float b) {
  return (uint_t)f2bf(a) | ((uint_t)f2bf(b) << 16);
}
__device__ __forceinline__ void unpk(uint_t w, float& a, float& b) {
  a = __uint_as_float(w << 16);
  b = __uint_as_float(w & 0xFFFF0000u);
}

// ---------------------------------------------------------------------------
// fp32 -> bf16, 8 elements/thread. n divisible by 8.
// ---------------------------------------------------------------------------
__global__ void fsta_cvt8(const float* __restrict__ src,
                          ushort_t* __restrict__ dst, int n) {
  int i = (blockIdx.x * 256 + threadIdx.x) * 8;
  if (i >= n) return;
  const float* f = src + i;
  uint4 u;
  u.x = pack2(f[0], f[1]); u.y = pack2(f[2], f[3]);
  u.z = pack2(f[4], f[5]); u.w = pack2(f[6], f[7]);
  *(uint4*)(dst + i) = u;
}

// Transpose + convert: src fp32 [R][Cc] -> dst bf16 [Cc][R].
__global__ void fsta_transpose_cvt(const float* __restrict__ src,
                                   ushort_t* __restrict__ dst, int R, int Cc) {
  int o = blockIdx.x * 256 + threadIdx.x;
  if (o >= R * Cc) return;
  int c = o / R;
  int r = o - c * R;
  dst[o] = f2bf(src[(size_t)r * Cc + c]);
}

// ---------------------------------------------------------------------------
// bf16 MFMA GEMM:  C[M,N] = A[M,K] @ Bt[N,K]^T  (+ optional fp32 bias[N])
// 128x128 tile, BK=32, 4 waves, each wave 64x64 via 4x4 of 16x16x32 MFMA.
// Layouts (learn_hip m89/m91): A frag A[m=lane&15][k=(lane>>4)*8+j],
// B frag B[k=(lane>>4)*8+j][n=lane&15], C/D col=lane&15 row=(lane>>4)*4+reg.
// LDS row stride 56 bf16 = 112 B (16B-aligned, <=2-way bank alias = free).
// OutT = ushort_t (bf16, internal buffers) or float (final output).
// ---------------------------------------------------------------------------
template <typename OutT>
__global__ __launch_bounds__(256) void fsta_gemm_bt(
    const ushort_t* __restrict__ A1,
    const ushort_t* __restrict__ Bt,
    const float* __restrict__ bias,
    OutT* __restrict__ Cout,
    int Ncols, int K)
{
  __shared__ ushort_t As[128 * 56];
  __shared__ ushort_t Bs[128 * 56];
  const int tid  = threadIdx.x;
  const int m0   = blockIdx.x * 128;
  const int n0   = blockIdx.y * 128;
  const int lane = tid & 63;
  const int wv   = tid >> 6;
  const int wr   = (wv >> 1) * 64;
  const int wc   = (wv & 1) * 64;
  const int lrow = lane & 15;
  const int lk8  = (lane >> 4) * 8;

  floatx4 acc[4][4];
#pragma unroll
  for (int i = 0; i < 4; ++i)
#pragma unroll
    for (int j = 0; j < 4; ++j)
      acc[i][j] = (floatx4){0.f, 0.f, 0.f, 0.f};

  const int srow = tid >> 1;          // 0..127
  const int scol = (tid & 1) * 16;    // 0 or 16

  for (int k0 = 0; k0 < K; k0 += 32) {
    size_t aoff = (size_t)(m0 + srow) * K + (k0 + scol);
    uint4 a0 = *(const uint4*)(A1 + aoff);
    uint4 a1 = *(const uint4*)(A1 + aoff + 8);
    size_t boff = (size_t)(n0 + srow) * K + (k0 + scol);
    uint4 w0 = *(const uint4*)(Bt + boff);
    uint4 w1 = *(const uint4*)(Bt + boff + 8);

    *(uint4*)&As[srow * 56 + scol]     = a0;
    *(uint4*)&As[srow * 56 + scol + 8] = a1;
    *(uint4*)&Bs[srow * 56 + scol]     = w0;
    *(uint4*)&Bs[srow * 56 + scol + 8] = w1;
    __syncthreads();

    short8 af[4], bfr[4];
#pragma unroll
    for (int i = 0; i < 4; ++i)
      af[i] = *(const short8*)&As[(wr + i * 16 + lrow) * 56 + lk8];
#pragma unroll
    for (int i = 0; i < 4; ++i)
      bfr[i] = *(const short8*)&Bs[(wc + i * 16 + lrow) * 56 + lk8];

#pragma unroll
    for (int i = 0; i < 4; ++i)
#pragma unroll
      for (int j = 0; j < 4; ++j)
        acc[i][j] = __builtin_amdgcn_mfma_f32_16x16x32_bf16(
            af[i], bfr[j], acc[i][j], 0, 0, 0);
    __syncthreads();
  }

  const int qd = lane >> 4;
#pragma unroll
  for (int i = 0; i < 4; ++i) {
    int row = m0 + wr + i * 16 + qd * 4;
#pragma unroll
    for (int j = 0; j < 4; ++j) {
      int col = n0 + wc + j * 16 + lrow;
      float badd = bias ? bias[col] : 0.f;
#pragma unroll
      for (int r = 0; r < 4; ++r) {
        float v = acc[i][j][r] + badd;
        if constexpr (sizeof(OutT) == 4)
          Cout[(size_t)(row + r) * Ncols + col] = v;
        else
          Cout[(size_t)(row + r) * Ncols + col] = (OutT)f2bf(v);
      }
    }
  }
}

// ---------------------------------------------------------------------------
// Spatial attention: one block per (b,t,h). K,V staged in LDS (50 KB).
// One thread per query row n (196 active of 256), fp32 online softmax.
// qkv row layout: [q(0..767) | k(768..1535) | v(1536..2303)], head h at h*64.
// ---------------------------------------------------------------------------
__global__ __launch_bounds__(256) void fsta_spatial(
    const ushort_t* __restrict__ qkv, ushort_t* __restrict__ x1)
{
  __shared__ ushort_t Ks[N_ * 64];
  __shared__ ushort_t Vs[N_ * 64];
  const int tid = threadIdx.x;
  const int bid = blockIdx.x;
  const int h   = bid % H_;
  const int bt  = bid / H_;
  const size_t rowbase = (size_t)bt * N_ * C3_;
  const int hofs = h * 64;

  for (int idx = tid; idx < N_ * 8; idx += 256) {
    int n = idx >> 3, c = (idx & 7) * 8;
    size_t so = rowbase + (size_t)n * C3_ + hofs + c;
    *(uint4*)&Ks[n * 64 + c] = *(const uint4*)(qkv + so + 768);
    *(uint4*)&Vs[n * 64 + c] = *(const uint4*)(qkv + so + 1536);
  }
  __syncthreads();
  if (tid >= N_) return;
  const int n = tid;

  float q[64];
  {
    const uint4* qp = (const uint4*)(qkv + rowbase + (size_t)n * C3_ + hofs);
#pragma unroll
    for (int c = 0; c < 8; ++c) {
      uint4 u = qp[c];
      unpk(u.x, q[c*8+0], q[c*8+1]);
      unpk(u.y, q[c*8+2], q[c*8+3]);
      unpk(u.z, q[c*8+4], q[c*8+5]);
      unpk(u.w, q[c*8+6], q[c*8+7]);
    }
  }

  float m = -INFINITY, l = 0.f, o[64];
#pragma unroll
  for (int d = 0; d < 64; ++d) o[d] = 0.f;

  for (int j = 0; j < N_; ++j) {
    const uint4* kr = (const uint4*)&Ks[j * 64];
    float s = 0.f;
#pragma unroll
    for (int c = 0; c < 8; ++c) {
      uint4 u = kr[c];
      float f0,f1,f2,f3,f4,f5,f6,f7;
      unpk(u.x,f0,f1); unpk(u.y,f2,f3); unpk(u.z,f4,f5); unpk(u.w,f6,f7);
      s = fmaf(q[c*8+0],f0,s); s = fmaf(q[c*8+1],f1,s);
      s = fmaf(q[c*8+2],f2,s); s = fmaf(q[c*8+3],f3,s);
      s = fmaf(q[c*8+4],f4,s); s = fmaf(q[c*8+5],f5,s);
      s = fmaf(q[c*8+6],f6,s); s = fmaf(q[c*8+7],f7,s);
    }
    s *= 0.125f;                      // hd^-0.5
    float mn = fmaxf(m, s);
    float al = __expf(m - mn);
    float p  = __expf(s - mn);
    l = l * al + p;
    m = mn;
    const uint4* vr = (const uint4*)&Vs[j * 64];
#pragma unroll
    for (int c = 0; c < 8; ++c) {
      uint4 u = vr[c];
      float f0,f1,f2,f3,f4,f5,f6,f7;
      unpk(u.x,f0,f1); unpk(u.y,f2,f3); unpk(u.z,f4,f5); unpk(u.w,f6,f7);
      o[c*8+0] = fmaf(p,f0, o[c*8+0]*al); o[c*8+1] = fmaf(p,f1, o[c*8+1]*al);
      o[c*8+2] = fmaf(p,f2, o[c*8+2]*al); o[c*8+3] = fmaf(p,f3, o[c*8+3]*al);
      o[c*8+4] = fmaf(p,f4, o[c*8+4]*al); o[c*8+5] = fmaf(p,f5, o[c*8+5]*al);
      o[c*8+6] = fmaf(p,f6, o[c*8+6]*al); o[c*8+7] = fmaf(p,f7, o[c*8+7]*al);
    }
  }

  float inv = 1.f / l;
  ushort_t* op = x1 + (size_t)(bt * N_ + n) * C_ + hofs;
#pragma unroll
  for (int c = 0; c < 8; ++c) {
    uint4 u;
    u.x = pack2(o[c*8+0]*inv, o[c*8+1]*inv);
    u.y = pack2(o[c*8+2]*inv, o[c*8+3]*inv);
    u.z = pack2(o[c*8+4]*inv, o[c*8+5]*inv);
    u.w = pack2(o[c*8+6]*inv, o[c*8+7]*inv);
    *(uint4*)(op + c * 8) = u;
  }
}

// ---------------------------------------------------------------------------
// Temporal attention over T=16, one thread per (b,h,n,t). Consecutive 16
// threads share (b,h,n) -> K/V rows L1/L2-resident. Fuses avg: reads spatial
// x1 and writes 0.5*(x1+x2) back into the same buffer.
// ---------------------------------------------------------------------------
__global__ __launch_bounds__(256) void fsta_temporal(
    const ushort_t* __restrict__ qkv, ushort_t* __restrict__ xavg)
{
  int gid  = blockIdx.x * 256 + threadIdx.x;
  int t    = gid & 15;
  int rest = gid >> 4;
  int n    = rest % N_;
  int bh   = rest / N_;
  int h    = bh % H_;
  int b    = bh / H_;
  const int hofs = h * 64;

  float q[64];
  {
    const size_t qoff = ((size_t)((b * T_ + t) * N_ + n)) * C3_ + hofs;
    const uint4* qp = (const uint4*)(qkv + qoff);
#pragma unroll
    for (int c = 0; c < 8; ++c) {
      uint4 u = qp[c];
      unpk(u.x, q[c*8+0], q[c*8+1]);
      unpk(u.y, q[c*8+2], q[c*8+3]);
      unpk(u.z, q[c*8+4], q[c*8+5]);
      unpk(u.w, q[c*8+6], q[c*8+7]);
    }
  }

  float m = -INFINITY, l = 0.f, o[64];
#pragma unroll
  for (int d = 0; d < 64; ++d) o[d] = 0.f;

  for (int s = 0; s < T_; ++s) {
    const size_t koff = ((size_t)((b * T_ + s) * N_ + n)) * C3_ + hofs + 768;
    const uint4* kr = (const uint4*)(qkv + koff);
    float sv = 0.f;
#pragma unroll
    for (int c = 0; c < 8; ++c) {
      uint4 u = kr[c];
      float f0,f1,f2,f3,f4,f5,f6,f7;
      unpk(u.x,f0,f1); unpk(u.y,f2,f3); unpk(u.z,f4,f5); unpk(u.w,f6,f7);
      sv = fmaf(q[c*8+0],f0,sv); sv = fmaf(q[c*8+1],f1,sv);
      sv = fmaf(q[c*8+2],f2,sv); sv = fmaf(q[c*8+3],f3,sv);
      sv = fmaf(q[c*8+4],f4,sv); sv = fmaf(q[c*8+5],f5,sv);
      sv = fmaf(q[c*8+6],f6,sv); sv = fmaf(q[c*8+7],f7,sv);
    }
    sv *= 0.125f;
    float mn = fmaxf(m, sv);
    float al = __expf(m - mn);
    float p  = __expf(sv - mn);
    l = l * al + p;
    m = mn;
    const uint4* vr = (const uint4*)(qkv + koff + 768);
#pragma unroll
    for (int c = 0; c < 8; ++c) {
      uint4 u = vr[c];
      float f0,f1,f2,f3,f4,f5,f6,f7;
      unpk(u.x,f0,f1); unpk(u.y,f2,f3); unpk(u.z,f4,f5); unpk(u.w,f6,f7);
      o[c*8+0] = fmaf(p,f0, o[c*8+0]*al); o[c*8+1] = fmaf(p,f1, o[c*8+1]*al);
      o[c*8+2] = fmaf(p,f2, o[c*8+2]*al); o[c*8+3] = fmaf(p,f3, o[c*8+3]*al);
      o[c*8+4] = fmaf(p,f4, o[c*8+4]*al); o[c*8+5] = fmaf(p,f5, o[c*8+5]*al);
      o[c*8+6] = fmaf(p,f6, o[c*8+6]*al); o[c*8+7] = fmaf(p,f7, o[c*8+7]*al);
    }
  }

  float inv = 1.f / l;
  ushort_t* op = xavg + ((size_t)((b * T_ + t) * N_ + n)) * C_ + hofs;
#pragma unroll
  for (int c = 0; c < 8; ++c) {
    uint4 prev = *(const uint4*)(op + c * 8);   // spatial branch x1
    float p0,p1,p2,p3,p4,p5,p6,p7;
    unpk(prev.x,p0,p1); unpk(prev.y,p2,p3); unpk(prev.z,p4,p5); unpk(prev.w,p6,p7);
    uint4 u;
    u.x = pack2(0.5f*(p0 + o[c*8+0]*inv), 0.5f*(p1 + o[c*8+1]*inv));
    u.y = pack2(0.5f*(p2 + o[c*8+2]*inv), 0.5f*(p3 + o[c*8+3]*inv));
    u.z = pack2(0.5f*(p4 + o[c*8+4]*inv), 0.5f*(p5 + o[c*8+5]*inv));
    u.w = pack2(0.5f*(p6 + o[c*8+6]*inv), 0.5f*(p7 + o[c*8+7]*inv));
    *(uint4*)(op + c * 8) = u;
  }
}

// ---------------------------------------------------------------------------
// ws layout (bf16 elements):
//   WtQkv  @ 0          : 2304*768   = 1,769,472
//   WtProj @ 1,769,472  : 768*768    =   589,824
//   xbf    @ 2,359,296  : 25088*768  = 19,267,584   (aliased as xavg later)
//   qkv    @ 21,626,880 : 25088*2304 = 57,802,752
// total 79,429,632 elems = 158.9 MB
// Inputs are fp32 (reference dtypes); output is fp32.
// ---------------------------------------------------------------------------
extern "C" void kernel_launch(void* const* d_in, const int* in_sizes, int n_in,
                              void* d_out, int out_size, void* d_ws, size_t ws_size,
                              hipStream_t stream)
{
  (void)in_sizes; (void)n_in; (void)out_size; (void)ws_size;
  const float* x     = (const float*)d_in[0];
  const float* Wqkv  = (const float*)d_in[1];
  const float* Wproj = (const float*)d_in[2];
  const float* bproj = (const float*)d_in[3];
  float*    out = (float*)d_out;
  ushort_t* ws  = (ushort_t*)d_ws;

  ushort_t* WtQkv  = ws;
  ushort_t* WtProj = ws + 1769472;
  ushort_t* xbf    = ws + 2359296;   // also xavg after spatial
  ushort_t* xavg   = xbf;
  ushort_t* qkv    = ws + 21626880;

  // 1. normalize inputs to bf16
  fsta_cvt8<<<dim3(9408), dim3(256), 0, stream>>>(x, xbf, M_ * C_);
  fsta_transpose_cvt<<<dim3(6912), dim3(256), 0, stream>>>(Wqkv, WtQkv, 768, 2304);
  fsta_transpose_cvt<<<dim3(2304), dim3(256), 0, stream>>>(Wproj, WtProj, 768, 768);
  // 2. qkv = x @ W_qkv   : M=25088, N=2304, K=768   (bf16 out)
  fsta_gemm_bt<ushort_t><<<dim3(196, 18), dim3(256), 0, stream>>>(
      xbf, WtQkv, (const float*)nullptr, qkv, 2304, 768);
  // 3. spatial attention -> xavg (holds x1; aliases xbf, which is now dead)
  fsta_spatial<<<dim3(B_ * T_ * H_), dim3(256), 0, stream>>>(qkv, xavg);
  // 4. temporal attention, fused 0.5*(x1+x2) -> xavg
  fsta_temporal<<<dim3((B_ * H_ * N_ * T_) / 256), dim3(256), 0, stream>>>(
      qkv, xavg);
  // 5. out = xavg @ W_proj + b_proj : M=25088, N=768, K=768  (fp32 out)
  fsta_gemm_bt<float><<<dim3(196, 6), dim3(256), 0, stream>>>(
      xavg, WtProj, bproj, out, 768, 768);
}

// Round 5
// 541.643 us; speedup vs baseline: 1.8063x; 1.8063x over previous
//
#include <hip/hip_runtime.h>
#include <cstdint>
#include <cstddef>

typedef unsigned short ushort_t;
typedef unsigned int   uint_t;

#define B_   8
#define T_   16
#define N_   196
#define C_   768
#define H_   12
#define C3_  2304
#define M_   25088   // B_*T_*N_

// spatial-attention tiling
#define NP_  208     // N padded to 13 tiles of 16
#define KS_  72      // K LDS row stride (elems): 144 B, 16B-aligned, 2-way alias
#define VS_  232     // V^T LDS row stride: 464 B, 16B-aligned, 2-way alias
#define PS_  232     // P LDS row stride

typedef __attribute__((ext_vector_type(8))) short short8;
typedef __attribute__((ext_vector_type(4))) float floatx4;

__device__ __forceinline__ float bf2f(ushort_t u) {
  return __uint_as_float(((uint_t)u) << 16);
}
__device__ __forceinline__ ushort_t f2bf(float f) {
  uint_t u = __float_as_uint(f);
  u += 0x7FFFu + ((u >> 16) & 1u);   // round-to-nearest-even
  return (ushort_t)(u >> 16);
}
__device__ __forceinline__ uint_t pack2(float a, float b) {
  return (uint_t)f2bf(a) | ((uint_t)f2bf(b) << 16);
}
__device__ __forceinline__ void unpk(uint_t w, float& a, float& b) {
  a = __uint_as_float(w << 16);
  b = __uint_as_float(w & 0xFFFF0000u);
}

// ---------------------------------------------------------------------------
// fp32 -> bf16, 8 elements/thread. n divisible by 8.
// ---------------------------------------------------------------------------
__global__ void fsta_cvt8(const float* __restrict__ src,
                          ushort_t* __restrict__ dst, int n) {
  int i = (blockIdx.x * 256 + threadIdx.x) * 8;
  if (i >= n) return;
  const float* f = src + i;
  uint4 u;
  u.x = pack2(f[0], f[1]); u.y = pack2(f[2], f[3]);
  u.z = pack2(f[4], f[5]); u.w = pack2(f[6], f[7]);
  *(uint4*)(dst + i) = u;
}

// Transpose + convert: src fp32 [R][Cc] -> dst bf16 [Cc][R].
__global__ void fsta_transpose_cvt(const float* __restrict__ src,
                                   ushort_t* __restrict__ dst, int R, int Cc) {
  int o = blockIdx.x * 256 + threadIdx.x;
  if (o >= R * Cc) return;
  int c = o / R;
  int r = o - c * R;
  dst[o] = f2bf(src[(size_t)r * Cc + c]);
}

// ---------------------------------------------------------------------------
// bf16 MFMA GEMM:  C[M,N] = A[M,K] @ Bt[N,K]^T  (+ optional fp32 bias[N])
// 128x128 tile, BK=32, 4 waves, each wave 64x64 via 4x4 of 16x16x32 MFMA.
// Layouts (verified end-to-end, round 4 pass): A frag A[m=lane&15][k=quad*8+j],
// B frag B[k=quad*8+j][n=lane&15], C/D col=lane&15 row=quad*4+reg.
// ---------------------------------------------------------------------------
template <typename OutT>
__global__ __launch_bounds__(256) void fsta_gemm_bt(
    const ushort_t* __restrict__ A1,
    const ushort_t* __restrict__ Bt,
    const float* __restrict__ bias,
    OutT* __restrict__ Cout,
    int Ncols, int K)
{
  __shared__ ushort_t As[128 * 56];
  __shared__ ushort_t Bs[128 * 56];
  const int tid  = threadIdx.x;
  const int m0   = blockIdx.x * 128;
  const int n0   = blockIdx.y * 128;
  const int lane = tid & 63;
  const int wv   = tid >> 6;
  const int wr   = (wv >> 1) * 64;
  const int wc   = (wv & 1) * 64;
  const int lrow = lane & 15;
  const int lk8  = (lane >> 4) * 8;

  floatx4 acc[4][4];
#pragma unroll
  for (int i = 0; i < 4; ++i)
#pragma unroll
    for (int j = 0; j < 4; ++j)
      acc[i][j] = (floatx4){0.f, 0.f, 0.f, 0.f};

  const int srow = tid >> 1;          // 0..127
  const int scol = (tid & 1) * 16;    // 0 or 16

  for (int k0 = 0; k0 < K; k0 += 32) {
    size_t aoff = (size_t)(m0 + srow) * K + (k0 + scol);
    uint4 a0 = *(const uint4*)(A1 + aoff);
    uint4 a1 = *(const uint4*)(A1 + aoff + 8);
    size_t boff = (size_t)(n0 + srow) * K + (k0 + scol);
    uint4 w0 = *(const uint4*)(Bt + boff);
    uint4 w1 = *(const uint4*)(Bt + boff + 8);

    *(uint4*)&As[srow * 56 + scol]     = a0;
    *(uint4*)&As[srow * 56 + scol + 8] = a1;
    *(uint4*)&Bs[srow * 56 + scol]     = w0;
    *(uint4*)&Bs[srow * 56 + scol + 8] = w1;
    __syncthreads();

    short8 af[4], bfr[4];
#pragma unroll
    for (int i = 0; i < 4; ++i)
      af[i] = *(const short8*)&As[(wr + i * 16 + lrow) * 56 + lk8];
#pragma unroll
    for (int i = 0; i < 4; ++i)
      bfr[i] = *(const short8*)&Bs[(wc + i * 16 + lrow) * 56 + lk8];

#pragma unroll
    for (int i = 0; i < 4; ++i)
#pragma unroll
      for (int j = 0; j < 4; ++j)
        acc[i][j] = __builtin_amdgcn_mfma_f32_16x16x32_bf16(
            af[i], bfr[j], acc[i][j], 0, 0, 0);
    __syncthreads();
  }

  const int qd = lane >> 4;
#pragma unroll
  for (int i = 0; i < 4; ++i) {
    int row = m0 + wr + i * 16 + qd * 4;
#pragma unroll
    for (int j = 0; j < 4; ++j) {
      int col = n0 + wc + j * 16 + lrow;
      float badd = bias ? bias[col] : 0.f;
#pragma unroll
      for (int r = 0; r < 4; ++r) {
        float v = acc[i][j][r] + badd;
        if constexpr (sizeof(OutT) == 4)
          Cout[(size_t)(row + r) * Ncols + col] = v;
        else
          Cout[(size_t)(row + r) * Ncols + col] = (OutT)f2bf(v);
      }
    }
  }
}

// ---------------------------------------------------------------------------
// Spatial attention, MFMA version. One block per (b,t,h), 4 waves.
// S = Q K^T over 13x13 tiles of 16 (N=196 padded to 208), full-row softmax
// in registers, P -> LDS round-trip (C/D layout -> A-frag layout), O = P V
// with V staged transposed. Pad cols masked to -inf pre-max; V^T/P pad
// cols zeroed so 0*garbage can't produce NaN.
// ---------------------------------------------------------------------------
__global__ __launch_bounds__(256) void fsta_spatial(
    const ushort_t* __restrict__ qkv, ushort_t* __restrict__ x1)
{
  __shared__ ushort_t Ks[NP_ * KS_];       // [key][dim]   29,952 B
  __shared__ ushort_t Vt[64 * VS_];        // [dim][key]   29,696 B
  __shared__ ushort_t Ps[4][16 * PS_];     // per-wave P   29,696 B
  const int tid = threadIdx.x;
  const int bid = blockIdx.x;
  const int h   = bid % H_;
  const int bt  = bid / H_;
  const size_t rowbase = (size_t)bt * N_ * C3_;
  const int hofs = h * 64;

  // stage K row-major and V transposed
  for (int idx = tid; idx < N_ * 8; idx += 256) {
    int n = idx >> 3, c = (idx & 7) * 8;
    size_t so = rowbase + (size_t)n * C3_ + hofs + c;
    *(uint4*)&Ks[n * KS_ + c] = *(const uint4*)(qkv + so + 768);
    uint4 v = *(const uint4*)(qkv + so + 1536);
    ushort_t tmp[8];
    *(uint4*)tmp = v;
#pragma unroll
    for (int i = 0; i < 8; ++i) Vt[(c + i) * VS_ + n] = tmp[i];
  }
  // zero V^T pad cols 196..231
  for (int idx = tid; idx < 64 * (VS_ - N_); idx += 256) {
    int d = idx / (VS_ - N_), k = N_ + idx % (VS_ - N_);
    Vt[d * VS_ + k] = 0;
  }
  __syncthreads();

  const int lane = tid & 63;
  const int wv   = tid >> 6;
  const int lrow = lane & 15;
  const int quad = lane >> 4;
  const int k8   = quad * 8;

  for (int qt = wv; qt < 13; qt += 4) {
    // Q A-frags straight from global (rows clamped; results discarded at store)
    int qrow = qt * 16 + lrow; if (qrow > N_ - 1) qrow = N_ - 1;
    const ushort_t* qp = qkv + rowbase + (size_t)qrow * C3_ + hofs;
    short8 qf0 = *(const short8*)(qp + k8);
    short8 qf1 = *(const short8*)(qp + 32 + k8);

    // S = Q K^T : 13 key tiles, K-dim 64 = 2 MFMA steps
    floatx4 s[13];
#pragma unroll
    for (int kt = 0; kt < 13; ++kt) {
      const ushort_t* kp = &Ks[(kt * 16 + lrow) * KS_];
      short8 kf0 = *(const short8*)(kp + k8);
      short8 kf1 = *(const short8*)(kp + 32 + k8);
      floatx4 a = (floatx4){0.f, 0.f, 0.f, 0.f};
      a = __builtin_amdgcn_mfma_f32_16x16x32_bf16(qf0, kf0, a, 0, 0, 0);
      a = __builtin_amdgcn_mfma_f32_16x16x32_bf16(qf1, kf1, a, 0, 0, 0);
      s[kt] = a;
    }

    // mask pad cols (tile 12, cols 196..207) before max
    if (lrow >= 4)
      s[12] = (floatx4){-INFINITY, -INFINITY, -INFINITY, -INFINITY};

    // row max + exp + row sum (rows = quad*4+r, cols spread over 16 lanes)
    float mx[4], sum[4];
#pragma unroll
    for (int r = 0; r < 4; ++r) {
      float m2 = s[0][r];
#pragma unroll
      for (int kt = 1; kt < 13; ++kt) m2 = fmaxf(m2, s[kt][r]);
#pragma unroll
      for (int xm = 1; xm < 16; xm <<= 1) m2 = fmaxf(m2, __shfl_xor(m2, xm, 64));
      mx[r] = m2;
    }
#pragma unroll
    for (int r = 0; r < 4; ++r) {
      float sm = 0.f;
#pragma unroll
      for (int kt = 0; kt < 13; ++kt) {
        float p = __expf((s[kt][r] - mx[r]) * 0.125f);   // scale folded in
        s[kt][r] = p;
        sm += p;
      }
#pragma unroll
      for (int xm = 1; xm < 16; xm <<= 1) sm += __shfl_xor(sm, xm, 64);
      sum[r] = sm;
    }

    // P: C/D layout -> LDS (bf16), pad cols 208..223 zeroed
    ushort_t* pw = Ps[wv];
#pragma unroll
    for (int kt = 0; kt < 13; ++kt)
#pragma unroll
      for (int r = 0; r < 4; ++r)
        pw[(quad * 4 + r) * PS_ + kt * 16 + lrow] = f2bf(s[kt][r]);
#pragma unroll
    for (int r = 0; r < 4; ++r)
      pw[(quad * 4 + r) * PS_ + 208 + lrow] = 0;

    // O = P V : A-frag from Ps, B-frag from Vt, 7 k-steps of 32 (224 cols)
    floatx4 o[4];
#pragma unroll
    for (int nt = 0; nt < 4; ++nt) o[nt] = (floatx4){0.f, 0.f, 0.f, 0.f};
#pragma unroll
    for (int kt = 0; kt < 7; ++kt) {
      short8 pf = *(const short8*)&pw[lrow * PS_ + kt * 32 + k8];
#pragma unroll
      for (int nt = 0; nt < 4; ++nt) {
        short8 vf = *(const short8*)&Vt[(nt * 16 + lrow) * VS_ + kt * 32 + k8];
        o[nt] = __builtin_amdgcn_mfma_f32_16x16x32_bf16(pf, vf, o[nt], 0, 0, 0);
      }
    }

    // normalize + store (D rows quad*4+r match sum[r] lanes)
    float inv[4];
#pragma unroll
    for (int r = 0; r < 4; ++r) inv[r] = 1.f / sum[r];
#pragma unroll
    for (int nt = 0; nt < 4; ++nt) {
#pragma unroll
      for (int r = 0; r < 4; ++r) {
        int qr = qt * 16 + quad * 4 + r;
        if (qr < N_)
          x1[(size_t)(bt * N_ + qr) * C_ + hofs + nt * 16 + lrow] =
              f2bf(o[nt][r] * inv[r]);
      }
    }
  }
}

// ---------------------------------------------------------------------------
// Temporal attention over T=16, one thread per (b,h,n,t). Consecutive 16
// threads share (b,h,n) -> K/V rows L1/L2-resident. Fuses avg: reads spatial
// x1 and writes 0.5*(x1+x2) back into the same buffer.
// ---------------------------------------------------------------------------
__global__ __launch_bounds__(256) void fsta_temporal(
    const ushort_t* __restrict__ qkv, ushort_t* __restrict__ xavg)
{
  int gid  = blockIdx.x * 256 + threadIdx.x;
  int t    = gid & 15;
  int rest = gid >> 4;
  int n    = rest % N_;
  int bh   = rest / N_;
  int h    = bh % H_;
  int b    = bh / H_;
  const int hofs = h * 64;

  float q[64];
  {
    const size_t qoff = ((size_t)((b * T_ + t) * N_ + n)) * C3_ + hofs;
    const uint4* qp = (const uint4*)(qkv + qoff);
#pragma unroll
    for (int c = 0; c < 8; ++c) {
      uint4 u = qp[c];
      unpk(u.x, q[c*8+0], q[c*8+1]);
      unpk(u.y, q[c*8+2], q[c*8+3]);
      unpk(u.z, q[c*8+4], q[c*8+5]);
      unpk(u.w, q[c*8+6], q[c*8+7]);
    }
  }

  float m = -INFINITY, l = 0.f, o[64];
#pragma unroll
  for (int d = 0; d < 64; ++d) o[d] = 0.f;

  for (int s = 0; s < T_; ++s) {
    const size_t koff = ((size_t)((b * T_ + s) * N_ + n)) * C3_ + hofs + 768;
    const uint4* kr = (const uint4*)(qkv + koff);
    float sv = 0.f;
#pragma unroll
    for (int c = 0; c < 8; ++c) {
      uint4 u = kr[c];
      float f0,f1,f2,f3,f4,f5,f6,f7;
      unpk(u.x,f0,f1); unpk(u.y,f2,f3); unpk(u.z,f4,f5); unpk(u.w,f6,f7);
      sv = fmaf(q[c*8+0],f0,sv); sv = fmaf(q[c*8+1],f1,sv);
      sv = fmaf(q[c*8+2],f2,sv); sv = fmaf(q[c*8+3],f3,sv);
      sv = fmaf(q[c*8+4],f4,sv); sv = fmaf(q[c*8+5],f5,sv);
      sv = fmaf(q[c*8+6],f6,sv); sv = fmaf(q[c*8+7],f7,sv);
    }
    sv *= 0.125f;
    float mn = fmaxf(m, sv);
    float al = __expf(m - mn);
    float p  = __expf(sv - mn);
    l = l * al + p;
    m = mn;
    const uint4* vr = (const uint4*)(qkv + koff + 768);
#pragma unroll
    for (int c = 0; c < 8; ++c) {
      uint4 u = vr[c];
      float f0,f1,f2,f3,f4,f5,f6,f7;
      unpk(u.x,f0,f1); unpk(u.y,f2,f3); unpk(u.z,f4,f5); unpk(u.w,f6,f7);
      o[c*8+0] = fmaf(p,f0, o[c*8+0]*al); o[c*8+1] = fmaf(p,f1, o[c*8+1]*al);
      o[c*8+2] = fmaf(p,f2, o[c*8+2]*al); o[c*8+3] = fmaf(p,f3, o[c*8+3]*al);
      o[c*8+4] = fmaf(p,f4, o[c*8+4]*al); o[c*8+5] = fmaf(p,f5, o[c*8+5]*al);
      o[c*8+6] = fmaf(p,f6, o[c*8+6]*al); o[c*8+7] = fmaf(p,f7, o[c*8+7]*al);
    }
  }

  float inv = 1.f / l;
  ushort_t* op = xavg + ((size_t)((b * T_ + t) * N_ + n)) * C_ + hofs;
#pragma unroll
  for (int c = 0; c < 8; ++c) {
    uint4 prev = *(const uint4*)(op + c * 8);   // spatial branch x1
    float p0,p1,p2,p3,p4,p5,p6,p7;
    unpk(prev.x,p0,p1); unpk(prev.y,p2,p3); unpk(prev.z,p4,p5); unpk(prev.w,p6,p7);
    uint4 u;
    u.x = pack2(0.5f*(p0 + o[c*8+0]*inv), 0.5f*(p1 + o[c*8+1]*inv));
    u.y = pack2(0.5f*(p2 + o[c*8+2]*inv), 0.5f*(p3 + o[c*8+3]*inv));
    u.z = pack2(0.5f*(p4 + o[c*8+4]*inv), 0.5f*(p5 + o[c*8+5]*inv));
    u.w = pack2(0.5f*(p6 + o[c*8+6]*inv), 0.5f*(p7 + o[c*8+7]*inv));
    *(uint4*)(op + c * 8) = u;
  }
}

// ---------------------------------------------------------------------------
// ws layout (bf16 elements):
//   WtQkv  @ 0          : 2304*768   = 1,769,472
//   WtProj @ 1,769,472  : 768*768    =   589,824
//   xbf    @ 2,359,296  : 25088*768  = 19,267,584   (aliased as xavg later)
//   qkv    @ 21,626,880 : 25088*2304 = 57,802,752
// total 79,429,632 elems = 158.9 MB
// Inputs fp32, output fp32, internal compute bf16 MFMA.
// ---------------------------------------------------------------------------
extern "C" void kernel_launch(void* const* d_in, const int* in_sizes, int n_in,
                              void* d_out, int out_size, void* d_ws, size_t ws_size,
                              hipStream_t stream)
{
  (void)in_sizes; (void)n_in; (void)out_size; (void)ws_size;
  const float* x     = (const float*)d_in[0];
  const float* Wqkv  = (const float*)d_in[1];
  const float* Wproj = (const float*)d_in[2];
  const float* bproj = (const float*)d_in[3];
  float*    out = (float*)d_out;
  ushort_t* ws  = (ushort_t*)d_ws;

  ushort_t* WtQkv  = ws;
  ushort_t* WtProj = ws + 1769472;
  ushort_t* xbf    = ws + 2359296;   // also xavg after spatial
  ushort_t* xavg   = xbf;
  ushort_t* qkv    = ws + 21626880;

  // 1. normalize inputs to bf16
  fsta_cvt8<<<dim3(9408), dim3(256), 0, stream>>>(x, xbf, M_ * C_);
  fsta_transpose_cvt<<<dim3(6912), dim3(256), 0, stream>>>(Wqkv, WtQkv, 768, 2304);
  fsta_transpose_cvt<<<dim3(2304), dim3(256), 0, stream>>>(Wproj, WtProj, 768, 768);
  // 2. qkv = x @ W_qkv   : M=25088, N=2304, K=768   (bf16 out)
  fsta_gemm_bt<ushort_t><<<dim3(196, 18), dim3(256), 0, stream>>>(
      xbf, WtQkv, (const float*)nullptr, qkv, 2304, 768);
  // 3. spatial attention (MFMA) -> xavg (holds x1; aliases dead xbf)
  fsta_spatial<<<dim3(B_ * T_ * H_), dim3(256), 0, stream>>>(qkv, xavg);
  // 4. temporal attention, fused 0.5*(x1+x2) -> xavg
  fsta_temporal<<<dim3((B_ * H_ * N_ * T_) / 256), dim3(256), 0, stream>>>(
      qkv, xavg);
  // 5. out = xavg @ W_proj + b_proj : M=25088, N=768, K=768  (fp32 out)
  fsta_gemm_bt<float><<<dim3(196, 6), dim3(256), 0, stream>>>(
      xavg, WtProj, bproj, out, 768, 768);
}

// Round 6
// 532.071 us; speedup vs baseline: 1.8388x; 1.0180x over previous
//
#include <hip/hip_runtime.h>
#include <cstdint>
#include <cstddef>

typedef unsigned short ushort_t;
typedef unsigned int   uint_t;

#define B_   8
#define T_   16
#define N_   196
#define C_   768
#define H_   12
#define C3_  2304
#define M_   25088   // B_*T_*N_

// spatial-attention tiling
#define NP_  208     // N padded to 13 tiles of 16
#define KS_  72      // K LDS row stride (elems): 144 B, 16B-aligned, 2-way alias
#define VS_  232     // V^T LDS row stride: 464 B, 16B-aligned, 2-way alias
#define PS_  232     // P LDS row stride

typedef __attribute__((ext_vector_type(8))) short short8;
typedef __attribute__((ext_vector_type(4))) float floatx4;

__device__ __forceinline__ float bf2f(ushort_t u) {
  return __uint_as_float(((uint_t)u) << 16);
}
__device__ __forceinline__ ushort_t f2bf(float f) {
  uint_t u = __float_as_uint(f);
  u += 0x7FFFu + ((u >> 16) & 1u);   // round-to-nearest-even
  return (ushort_t)(u >> 16);
}
__device__ __forceinline__ uint_t pack2(float a, float b) {
  return (uint_t)f2bf(a) | ((uint_t)f2bf(b) << 16);
}
__device__ __forceinline__ void unpk(uint_t w, float& a, float& b) {
  a = __uint_as_float(w << 16);
  b = __uint_as_float(w & 0xFFFF0000u);
}

// async global->LDS, 16 B per lane. LDS dest = wave-uniform base + lane*16.
__device__ __forceinline__ void gload_lds16(const ushort_t* g, ushort_t* l) {
  __builtin_amdgcn_global_load_lds(
      (const __attribute__((address_space(1))) uint_t*)g,
      (__attribute__((address_space(3))) uint_t*)l, 16, 0, 0);
}

// ---------------------------------------------------------------------------
// fp32 -> bf16, 8 elements/thread. n divisible by 8.
// ---------------------------------------------------------------------------
__global__ void fsta_cvt8(const float* __restrict__ src,
                          ushort_t* __restrict__ dst, int n) {
  int i = (blockIdx.x * 256 + threadIdx.x) * 8;
  if (i >= n) return;
  const float* f = src + i;
  uint4 u;
  u.x = pack2(f[0], f[1]); u.y = pack2(f[2], f[3]);
  u.z = pack2(f[4], f[5]); u.w = pack2(f[6], f[7]);
  *(uint4*)(dst + i) = u;
}

// Transpose + convert: src fp32 [R][Cc] -> dst bf16 [Cc][R].
__global__ void fsta_transpose_cvt(const float* __restrict__ src,
                                   ushort_t* __restrict__ dst, int R, int Cc) {
  int o = blockIdx.x * 256 + threadIdx.x;
  if (o >= R * Cc) return;
  int c = o / R;
  int r = o - c * R;
  dst[o] = f2bf(src[(size_t)r * Cc + c]);
}

// ---------------------------------------------------------------------------
// bf16 MFMA GEMM (m97 structure):  C[M,N] = A[M,K] @ Bt[N,K]^T (+ fp32 bias)
// 128x128 tile, BK=32, 4 waves, 4x4 of 16x16x32 MFMA per wave.
// Staging via global_load_lds width=16: LDS tiles are UNPADDED [128][32]
// (dest = wave-uniform base + lane*16 B, lane-contiguous layout mandatory).
// Per K-step each wave issues 2 A-chunks + 2 B-chunks (16 rows x 32 cols
// each); chunk ch covers rows ch*16..+15, lane l -> row l/4, col (l%3)*8.
// Frag layouts verified end-to-end (rounds 4-5).
// ---------------------------------------------------------------------------
template <typename OutT>
__global__ __launch_bounds__(256) void fsta_gemm_bt(
    const ushort_t* __restrict__ A1,
    const ushort_t* __restrict__ Bt,
    const float* __restrict__ bias,
    OutT* __restrict__ Cout,
    int Ncols, int K)
{
  __shared__ ushort_t As[128 * 32];
  __shared__ ushort_t Bs[128 * 32];
  const int tid  = threadIdx.x;
  const int m0   = blockIdx.x * 128;
  const int n0   = blockIdx.y * 128;
  const int lane = tid & 63;
  const int wv   = tid >> 6;
  const int wr   = (wv >> 1) * 64;
  const int wc   = (wv & 1) * 64;
  const int lrow = lane & 15;
  const int k8   = (lane >> 4) * 8;

  // staging coords: 4 lanes per row (16 B each), 16 rows per chunk
  const int srow = lane >> 2;          // 0..15
  const int scol = (lane & 3) * 8;     // 0,8,16,24

  floatx4 acc[4][4];
#pragma unroll
  for (int i = 0; i < 4; ++i)
#pragma unroll
    for (int j = 0; j < 4; ++j)
      acc[i][j] = (floatx4){0.f, 0.f, 0.f, 0.f};

  for (int k0 = 0; k0 < K; k0 += 32) {
#pragma unroll
    for (int i = 0; i < 2; ++i) {
      const int ch = wv * 2 + i;                    // 0..7
      const ushort_t* ga =
          A1 + (size_t)(m0 + ch * 16 + srow) * K + k0 + scol;
      gload_lds16(ga, &As[ch * 512]);               // 512 elems = 16 rows
      const ushort_t* gb =
          Bt + (size_t)(n0 + ch * 16 + srow) * K + k0 + scol;
      gload_lds16(gb, &Bs[ch * 512]);
    }
    __syncthreads();                                // drains vmcnt

    short8 af[4], bfr[4];
#pragma unroll
    for (int i = 0; i < 4; ++i)
      af[i] = *(const short8*)&As[(wr + i * 16 + lrow) * 32 + k8];
#pragma unroll
    for (int i = 0; i < 4; ++i)
      bfr[i] = *(const short8*)&Bs[(wc + i * 16 + lrow) * 32 + k8];

#pragma unroll
    for (int i = 0; i < 4; ++i)
#pragma unroll
      for (int j = 0; j < 4; ++j)
        acc[i][j] = __builtin_amdgcn_mfma_f32_16x16x32_bf16(
            af[i], bfr[j], acc[i][j], 0, 0, 0);
    __syncthreads();
  }

  const int qd = lane >> 4;
#pragma unroll
  for (int i = 0; i < 4; ++i) {
    int row = m0 + wr + i * 16 + qd * 4;
#pragma unroll
    for (int j = 0; j < 4; ++j) {
      int col = n0 + wc + j * 16 + lrow;
      float badd = bias ? bias[col] : 0.f;
#pragma unroll
      for (int r = 0; r < 4; ++r) {
        float v = acc[i][j][r] + badd;
        if constexpr (sizeof(OutT) == 4)
          Cout[(size_t)(row + r) * Ncols + col] = v;
        else
          Cout[(size_t)(row + r) * Ncols + col] = (OutT)f2bf(v);
      }
    }
  }
}

// ---------------------------------------------------------------------------
// Spatial attention, MFMA version. One block per (b,t,h), 4 waves.
// S = Q K^T over 13x13 tiles of 16 (N=196 padded to 208), full-row softmax
// in registers, P -> LDS round-trip (C/D layout -> A-frag layout), O = P V
// with V staged transposed. Pad cols masked to -inf pre-max; V^T/P pad
// cols zeroed so 0*garbage can't produce NaN.
// ---------------------------------------------------------------------------
__global__ __launch_bounds__(256) void fsta_spatial(
    const ushort_t* __restrict__ qkv, ushort_t* __restrict__ x1)
{
  __shared__ ushort_t Ks[NP_ * KS_];       // [key][dim]   29,952 B
  __shared__ ushort_t Vt[64 * VS_];        // [dim][key]   29,696 B
  __shared__ ushort_t Ps[4][16 * PS_];     // per-wave P   29,696 B
  const int tid = threadIdx.x;
  const int bid = blockIdx.x;
  const int h   = bid % H_;
  const int bt  = bid / H_;
  const size_t rowbase = (size_t)bt * N_ * C3_;
  const int hofs = h * 64;

  // stage K row-major and V transposed
  for (int idx = tid; idx < N_ * 8; idx += 256) {
    int n = idx >> 3, c = (idx & 7) * 8;
    size_t so = rowbase + (size_t)n * C3_ + hofs + c;
    *(uint4*)&Ks[n * KS_ + c] = *(const uint4*)(qkv + so + 768);
    uint4 v = *(const uint4*)(qkv + so + 1536);
    ushort_t tmp[8];
    *(uint4*)tmp = v;
#pragma unroll
    for (int i = 0; i < 8; ++i) Vt[(c + i) * VS_ + n] = tmp[i];
  }
  // zero V^T pad cols 196..231
  for (int idx = tid; idx < 64 * (VS_ - N_); idx += 256) {
    int d = idx / (VS_ - N_), k = N_ + idx % (VS_ - N_);
    Vt[d * VS_ + k] = 0;
  }
  __syncthreads();

  const int lane = tid & 63;
  const int wv   = tid >> 6;
  const int lrow = lane & 15;
  const int quad = lane >> 4;
  const int k8   = quad * 8;

  for (int qt = wv; qt < 13; qt += 4) {
    // Q A-frags straight from global (rows clamped; results discarded at store)
    int qrow = qt * 16 + lrow; if (qrow > N_ - 1) qrow = N_ - 1;
    const ushort_t* qp = qkv + rowbase + (size_t)qrow * C3_ + hofs;
    short8 qf0 = *(const short8*)(qp + k8);
    short8 qf1 = *(const short8*)(qp + 32 + k8);

    // S = Q K^T : 13 key tiles, K-dim 64 = 2 MFMA steps
    floatx4 s[13];
#pragma unroll
    for (int kt = 0; kt < 13; ++kt) {
      const ushort_t* kp = &Ks[(kt * 16 + lrow) * KS_];
      short8 kf0 = *(const short8*)(kp + k8);
      short8 kf1 = *(const short8*)(kp + 32 + k8);
      floatx4 a = (floatx4){0.f, 0.f, 0.f, 0.f};
      a = __builtin_amdgcn_mfma_f32_16x16x32_bf16(qf0, kf0, a, 0, 0, 0);
      a = __builtin_amdgcn_mfma_f32_16x16x32_bf16(qf1, kf1, a, 0, 0, 0);
      s[kt] = a;
    }

    // mask pad cols (tile 12, cols 196..207) before max
    if (lrow >= 4)
      s[12] = (floatx4){-INFINITY, -INFINITY, -INFINITY, -INFINITY};

    // row max + exp + row sum (rows = quad*4+r, cols spread over 16 lanes)
    float mx[4], sum[4];
#pragma unroll
    for (int r = 0; r < 4; ++r) {
      float m2 = s[0][r];
#pragma unroll
      for (int kt = 1; kt < 13; ++kt) m2 = fmaxf(m2, s[kt][r]);
#pragma unroll
      for (int xm = 1; xm < 16; xm <<= 1) m2 = fmaxf(m2, __shfl_xor(m2, xm, 64));
      mx[r] = m2;
    }
#pragma unroll
    for (int r = 0; r < 4; ++r) {
      float sm = 0.f;
#pragma unroll
      for (int kt = 0; kt < 13; ++kt) {
        float p = __expf((s[kt][r] - mx[r]) * 0.125f);   // scale folded in
        s[kt][r] = p;
        sm += p;
      }
#pragma unroll
      for (int xm = 1; xm < 16; xm <<= 1) sm += __shfl_xor(sm, xm, 64);
      sum[r] = sm;
    }

    // P: C/D layout -> LDS (bf16), pad cols 208..223 zeroed
    ushort_t* pw = Ps[wv];
#pragma unroll
    for (int kt = 0; kt < 13; ++kt)
#pragma unroll
      for (int r = 0; r < 4; ++r)
        pw[(quad * 4 + r) * PS_ + kt * 16 + lrow] = f2bf(s[kt][r]);
#pragma unroll
    for (int r = 0; r < 4; ++r)
      pw[(quad * 4 + r) * PS_ + 208 + lrow] = 0;

    // O = P V : A-frag from Ps, B-frag from Vt, 7 k-steps of 32 (224 cols)
    floatx4 o[4];
#pragma unroll
    for (int nt = 0; nt < 4; ++nt) o[nt] = (floatx4){0.f, 0.f, 0.f, 0.f};
#pragma unroll
    for (int kt = 0; kt < 7; ++kt) {
      short8 pf = *(const short8*)&pw[lrow * PS_ + kt * 32 + k8];
#pragma unroll
      for (int nt = 0; nt < 4; ++nt) {
        short8 vf = *(const short8*)&Vt[(nt * 16 + lrow) * VS_ + kt * 32 + k8];
        o[nt] = __builtin_amdgcn_mfma_f32_16x16x32_bf16(pf, vf, o[nt], 0, 0, 0);
      }
    }

    // normalize + store (D rows quad*4+r match sum[r] lanes)
    float inv[4];
#pragma unroll
    for (int r = 0; r < 4; ++r) inv[r] = 1.f / sum[r];
#pragma unroll
    for (int nt = 0; nt < 4; ++nt) {
#pragma unroll
      for (int r = 0; r < 4; ++r) {
        int qr = qt * 16 + quad * 4 + r;
        if (qr < N_)
          x1[(size_t)(bt * N_ + qr) * C_ + hofs + nt * 16 + lrow] =
              f2bf(o[nt][r] * inv[r]);
      }
    }
  }
}

// ---------------------------------------------------------------------------
// Temporal attention over T=16, one thread per (b,h,n,t). Consecutive 16
// threads share (b,h,n) -> K/V rows L1/L2-resident. Fuses avg: reads spatial
// x1 and writes 0.5*(x1+x2) back into the same buffer.
// ---------------------------------------------------------------------------
__global__ __launch_bounds__(256) void fsta_temporal(
    const ushort_t* __restrict__ qkv, ushort_t* __restrict__ xavg)
{
  int gid  = blockIdx.x * 256 + threadIdx.x;
  int t    = gid & 15;
  int rest = gid >> 4;
  int n    = rest % N_;
  int bh   = rest / N_;
  int h    = bh % H_;
  int b    = bh / H_;
  const int hofs = h * 64;

  float q[64];
  {
    const size_t qoff = ((size_t)((b * T_ + t) * N_ + n)) * C3_ + hofs;
    const uint4* qp = (const uint4*)(qkv + qoff);
#pragma unroll
    for (int c = 0; c < 8; ++c) {
      uint4 u = qp[c];
      unpk(u.x, q[c*8+0], q[c*8+1]);
      unpk(u.y, q[c*8+2], q[c*8+3]);
      unpk(u.z, q[c*8+4], q[c*8+5]);
      unpk(u.w, q[c*8+6], q[c*8+7]);
    }
  }

  float m = -INFINITY, l = 0.f, o[64];
#pragma unroll
  for (int d = 0; d < 64; ++d) o[d] = 0.f;

  for (int s = 0; s < T_; ++s) {
    const size_t koff = ((size_t)((b * T_ + s) * N_ + n)) * C3_ + hofs + 768;
    const uint4* kr = (const uint4*)(qkv + koff);
    float sv = 0.f;
#pragma unroll
    for (int c = 0; c < 8; ++c) {
      uint4 u = kr[c];
      float f0,f1,f2,f3,f4,f5,f6,f7;
      unpk(u.x,f0,f1); unpk(u.y,f2,f3); unpk(u.z,f4,f5); unpk(u.w,f6,f7);
      sv = fmaf(q[c*8+0],f0,sv); sv = fmaf(q[c*8+1],f1,sv);
      sv = fmaf(q[c*8+2],f2,sv); sv = fmaf(q[c*8+3],f3,sv);
      sv = fmaf(q[c*8+4],f4,sv); sv = fmaf(q[c*8+5],f5,sv);
      sv = fmaf(q[c*8+6],f6,sv); sv = fmaf(q[c*8+7],f7,sv);
    }
    sv *= 0.125f;
    float mn = fmaxf(m, sv);
    float al = __expf(m - mn);
    float p  = __expf(sv - mn);
    l = l * al + p;
    m = mn;
    const uint4* vr = (const uint4*)(qkv + koff + 768);
#pragma unroll
    for (int c = 0; c < 8; ++c) {
      uint4 u = vr[c];
      float f0,f1,f2,f3,f4,f5,f6,f7;
      unpk(u.x,f0,f1); unpk(u.y,f2,f3); unpk(u.z,f4,f5); unpk(u.w,f6,f7);
      o[c*8+0] = fmaf(p,f0, o[c*8+0]*al); o[c*8+1] = fmaf(p,f1, o[c*8+1]*al);
      o[c*8+2] = fmaf(p,f2, o[c*8+2]*al); o[c*8+3] = fmaf(p,f3, o[c*8+3]*al);
      o[c*8+4] = fmaf(p,f4, o[c*8+4]*al); o[c*8+5] = fmaf(p,f5, o[c*8+5]*al);
      o[c*8+6] = fmaf(p,f6, o[c*8+6]*al); o[c*8+7] = fmaf(p,f7, o[c*8+7]*al);
    }
  }

  float inv = 1.f / l;
  ushort_t* op = xavg + ((size_t)((b * T_ + t) * N_ + n)) * C_ + hofs;
#pragma unroll
  for (int c = 0; c < 8; ++c) {
    uint4 prev = *(const uint4*)(op + c * 8);   // spatial branch x1
    float p0,p1,p2,p3,p4,p5,p6,p7;
    unpk(prev.x,p0,p1); unpk(prev.y,p2,p3); unpk(prev.z,p4,p5); unpk(prev.w,p6,p7);
    uint4 u;
    u.x = pack2(0.5f*(p0 + o[c*8+0]*inv), 0.5f*(p1 + o[c*8+1]*inv));
    u.y = pack2(0.5f*(p2 + o[c*8+2]*inv), 0.5f*(p3 + o[c*8+3]*inv));
    u.z = pack2(0.5f*(p4 + o[c*8+4]*inv), 0.5f*(p5 + o[c*8+5]*inv));
    u.w = pack2(0.5f*(p6 + o[c*8+6]*inv), 0.5f*(p7 + o[c*8+7]*inv));
    *(uint4*)(op + c * 8) = u;
  }
}

// ---------------------------------------------------------------------------
// ws layout (bf16 elements):
//   WtQkv  @ 0          : 2304*768   = 1,769,472
//   WtProj @ 1,769,472  : 768*768    =   589,824
//   xbf    @ 2,359,296  : 25088*768  = 19,267,584   (aliased as xavg later)
//   qkv    @ 21,626,880 : 25088*2304 = 57,802,752
// total 79,429,632 elems = 158.9 MB
// Inputs fp32, output fp32, internal compute bf16 MFMA.
// ---------------------------------------------------------------------------
extern "C" void kernel_launch(void* const* d_in, const int* in_sizes, int n_in,
                              void* d_out, int out_size, void* d_ws, size_t ws_size,
                              hipStream_t stream)
{
  (void)in_sizes; (void)n_in; (void)out_size; (void)ws_size;
  const float* x     = (const float*)d_in[0];
  const float* Wqkv  = (const float*)d_in[1];
  const float* Wproj = (const float*)d_in[2];
  const float* bproj = (const float*)d_in[3];
  float*    out = (float*)d_out;
  ushort_t* ws  = (ushort_t*)d_ws;

  ushort_t* WtQkv  = ws;
  ushort_t* WtProj = ws + 1769472;
  ushort_t* xbf    = ws + 2359296;   // also xavg after spatial
  ushort_t* xavg   = xbf;
  ushort_t* qkv    = ws + 21626880;

  // 1. normalize inputs to bf16
  fsta_cvt8<<<dim3(9408), dim3(256), 0, stream>>>(x, xbf, M_ * C_);
  fsta_transpose_cvt<<<dim3(6912), dim3(256), 0, stream>>>(Wqkv, WtQkv, 768, 2304);
  fsta_transpose_cvt<<<dim3(2304), dim3(256), 0, stream>>>(Wproj, WtProj, 768, 768);
  // 2. qkv = x @ W_qkv   : M=25088, N=2304, K=768   (bf16 out)
  fsta_gemm_bt<ushort_t><<<dim3(196, 18), dim3(256), 0, stream>>>(
      xbf, WtQkv, (const float*)nullptr, qkv, 2304, 768);
  // 3. spatial attention (MFMA) -> xavg (holds x1; aliases dead xbf)
  fsta_spatial<<<dim3(B_ * T_ * H_), dim3(256), 0, stream>>>(qkv, xavg);
  // 4. temporal attention, fused 0.5*(x1+x2) -> xavg
  fsta_temporal<<<dim3((B_ * H_ * N_ * T_) / 256), dim3(256), 0, stream>>>(
      qkv, xavg);
  // 5. out = xavg @ W_proj + b_proj : M=25088, N=768, K=768  (fp32 out)
  fsta_gemm_bt<float><<<dim3(196, 6), dim3(256), 0, stream>>>(
      xavg, WtProj, bproj, out, 768, 768);
}